// Round 1
// baseline (27799.963 us; speedup 1.0000x reference)
//
#include <hip/hip_runtime.h>
#include <hip/hip_bf16.h>
#include <stdint.h>

// Bidirectional 2-layer LSTM "decoder": B=16, T=512, E=H=1024, gates=4096.
// Architecture:
//   prep: bias-sum, embedding->bf16 X, fragment-pack all weights to bf16
//   k_l0: 128 blocks (2 cells x 64 j-tiles of 16), W_hh in LDS, W_ih streamed,
//         per-cell 64-block flag barrier per step, writes full h0 history
//   k_l1: 128 blocks, A = [h0f(t) | h0b(t) | h1(t-1)] (K=3072), hh part in LDS,
//         writes d_out (fp32) and h1 ring buffer.

#define TB 16
#define TT 512
#define HH 1024

typedef __bf16 bf16x8 __attribute__((ext_vector_type(8)));
typedef float f32x4 __attribute__((ext_vector_type(4)));
typedef unsigned int u32;
typedef unsigned short u16;

// ---- workspace layout (bytes) ----
#define OFS_CNT   0ul            // 4 u32 counters (zeroed each launch)
#define OFS_B0    256ul          // [2][4096] f32
#define OFS_B1    33024ul        // [2][4096] f32
#define OFS_X     65792ul        // [8192][1024] bf16
#define OFS_WIH0  16843008ul     // packed [2][64][4][32][64][8] bf16
#define OFS_WHH0  33620224ul     // packed, same shape
#define OFS_W1    50397440ul     // packed [2][64][4][96][64][8] bf16 (ih|hh, K=3072)
#define OFS_H0    100729088ul    // [512][2][16][1024] bf16 (h0 history)
#define OFS_H1    134283520ul    // [3][2][16][1024] bf16 (h1 ring)
// end ~134.5 MB

__device__ inline u16 f2b(float f){
  union { float f; u32 u; } x{f};
  return (u16)((x.u + 0x7FFFu + ((x.u >> 16) & 1u)) >> 16);
}
__device__ inline float sigm(float x){ return 1.f/(1.f + __expf(-x)); }
__device__ inline float tanh_(float x){ return 2.f*sigm(2.f*x) - 1.f; }

union AF { uint2 u2[2]; bf16x8 v; };
__device__ inline bf16x8 load_af(const u16* p){
  AF a; a.u2[0] = *(const uint2*)p; a.u2[1] = *(const uint2*)(p + 16); return a.v;
}

__global__ void k_bias(const float* __restrict__ a0, const float* __restrict__ a1,
                       const float* __restrict__ a2, const float* __restrict__ a3,
                       float* __restrict__ b0, float* __restrict__ b1){
  int i = blockIdx.x*256 + threadIdx.x;
  if (i < 8192){ b0[i] = a0[i] + a1[i]; b1[i] = a2[i] + a3[i]; }
}

__global__ void k_embed(const int* __restrict__ inputs, const float* __restrict__ emb,
                        u16* __restrict__ X){
  int row = blockIdx.x;                 // t*16 + b
  int t = row >> 4, b = row & 15;
  int tok = (t == 0) ? 1 : inputs[b*TT + t];   // BOS=1 at t=0
  const float4* src = (const float4*)(emb + (size_t)tok*HH);
  float4 v = src[threadIdx.x];
  ushort4 o = make_ushort4(f2b(v.x), f2b(v.y), f2b(v.z), f2b(v.w));
  ((ushort4*)X)[(size_t)row*256 + threadIdx.x] = o;
}

// pack W[n][k] (fp32, per cell) -> fragment-major bf16:
// dst frag index ((((cell*64+jb)*4+g)*KS+ks)*64+l), elem j <-> k = ks*32+4*(l>>4)+(j&3)+16*(j>>2)
__global__ void k_pack(const float* __restrict__ sA, const float* __restrict__ sB,
                       int KA, int KB, u16* __restrict__ dst){
  int K = KA + KB, KS = K >> 5;
  long idx = (long)blockIdx.x*256 + threadIdx.x;
  long total = 2L*64*4*KS*64;
  if (idx >= total) return;
  int l = (int)(idx & 63);
  long r = idx >> 6;
  int ks = (int)(r % KS); r /= KS;
  int g  = (int)(r & 3);  r >>= 2;
  int jb = (int)(r & 63); r >>= 6;
  int cell = (int)r;
  int n  = g*1024 + jb*16 + (l & 15);
  int k0 = ks*32 + ((l >> 4) << 2);
  union { u16 v[8]; int4 q; } o;
  for (int h = 0; h < 2; h++){
    int kk = k0 + h*16;
    const float* s; int kl;
    if (kk < KA){ s = sA + ((long)cell*4096 + n)*KA; kl = kk; }
    else        { s = sB + ((long)cell*4096 + n)*KB; kl = kk - KA; }
    float4 f = *(const float4*)(s + kl);
    o.v[h*4+0]=f2b(f.x); o.v[h*4+1]=f2b(f.y); o.v[h*4+2]=f2b(f.z); o.v[h*4+3]=f2b(f.w);
  }
  long d = ((((long)cell*64 + jb)*4 + g)*KS + ks)*64 + l;
  ((int4*)dst)[d] = o.q;
}

// -------- layer 0: gates = b0 + X[t]@Wih^T + h0[t-1]@Whh^T --------
__global__ __launch_bounds__(256, 1)
void k_l0(const u16* __restrict__ Wih0p, const u16* __restrict__ Whh0p,
          const float* __restrict__ b0, const u16* __restrict__ Xb,
          u16* h0_all, u32* cnt){
  extern __shared__ char smem[];
  int4* wlds = (int4*)smem;                 // [4][32][64] frags (131072 B)
  float* gl  = (float*)(smem + 131072);     // [4][16][16] gates
  const int bid = blockIdx.x, cell = bid >> 6, jb = bid & 63;
  const int tid = threadIdx.x, wv = tid >> 6, l = tid & 63;

  const int4* wsrc = (const int4*)Whh0p + ((long)cell*64 + jb)*8192;
  for (int i = tid; i < 8192; i += 256) wlds[i] = wsrc[i];
  __syncthreads();

  const float bias = b0[cell*4096 + wv*1024 + jb*16 + (l & 15)];
  const bf16x8* wih = (const bf16x8*)Wih0p + (((long)cell*64 + jb)*4 + wv)*2048;
  const bf16x8* whh = (const bf16x8*)smem + wv*2048;
  const int rowA = l & 15, kq = (l >> 4) << 2;
  u32* myc = cnt + cell;
  const int b_ = tid >> 4, j = tid & 15;
  float creg = 0.f;

  for (int t = 0; t < TT; t++){
    if (t > 0){
      const u32 target = 64u * (u32)t;
      if (tid == 0){
        while (__hip_atomic_load(myc, __ATOMIC_RELAXED, __HIP_MEMORY_SCOPE_AGENT) < target)
          __builtin_amdgcn_s_sleep(2);
        __threadfence();
      }
      __syncthreads();
    }
    f32x4 acc[4] = {{bias,bias,bias,bias},{0,0,0,0},{0,0,0,0},{0,0,0,0}};
    {
      const u16* Ar = Xb + ((long)t*16 + rowA)*1024;
      #pragma unroll
      for (int ks = 0; ks < 32; ks++){
        bf16x8 bf_ = wih[ks*64 + l];
        bf16x8 af  = load_af(Ar + ks*32 + kq);
        acc[ks & 3] = __builtin_amdgcn_mfma_f32_16x16x32_bf16(af, bf_, acc[ks & 3], 0, 0, 0);
      }
    }
    if (t > 0){
      const u16* Ar = h0_all + (((long)(t-1)*2 + cell)*16 + rowA)*1024;
      #pragma unroll
      for (int ks = 0; ks < 32; ks++){
        bf16x8 bf_ = whh[ks*64 + l];
        bf16x8 af  = load_af(Ar + ks*32 + kq);
        acc[ks & 3] = __builtin_amdgcn_mfma_f32_16x16x32_bf16(af, bf_, acc[ks & 3], 0, 0, 0);
      }
    }
    f32x4 a = acc[0] + acc[1] + acc[2] + acc[3];
    const int r0 = (l >> 4) << 2, cj = l & 15;
    gl[wv*256 + (r0+0)*16 + cj] = a[0];
    gl[wv*256 + (r0+1)*16 + cj] = a[1];
    gl[wv*256 + (r0+2)*16 + cj] = a[2];
    gl[wv*256 + (r0+3)*16 + cj] = a[3];
    __syncthreads();
    {
      float gi = gl[tid], gf = gl[256 + tid], gg = gl[512 + tid], go = gl[768 + tid];
      float c2 = sigm(gf)*creg + sigm(gi)*tanh_(gg);
      float h2 = sigm(go)*tanh_(c2);
      creg = c2;
      h0_all[(((long)t*2 + cell)*16 + b_)*1024 + jb*16 + j] = f2b(h2);
    }
    __syncthreads();
    if (tid == 0){
      __threadfence();
      __hip_atomic_fetch_add(myc, 1u, __ATOMIC_RELEASE, __HIP_MEMORY_SCOPE_AGENT);
    }
  }
}

// -------- layer 1: gates = b1 + [h0f|h0b](t)@Wih^T + h1(t-1)@Whh^T; out = h1 --------
__global__ __launch_bounds__(256, 1)
void k_l1(const u16* __restrict__ W1p, const float* __restrict__ b1,
          const u16* __restrict__ h0_all, u16* h1r,
          float* __restrict__ out, u32* cnt){
  extern __shared__ char smem[];
  int4* wlds = (int4*)smem;                 // hh part: [4][32][64] frags
  float* gl  = (float*)(smem + 131072);
  const int bid = blockIdx.x, cell = bid >> 6, jb = bid & 63;
  const int tid = threadIdx.x, wv = tid >> 6, l = tid & 63;

  const int4* wbase = (const int4*)W1p + ((long)cell*64 + jb)*24576;   // 4*96*64
  for (int i = tid; i < 8192; i += 256){
    int g = i >> 11, ks2 = (i >> 6) & 31, ll = i & 63;
    wlds[i] = wbase[(g*96 + 64 + ks2)*64 + ll];
  }
  __syncthreads();

  const float bias = b1[cell*4096 + wv*1024 + jb*16 + (l & 15)];
  const bf16x8* wih = (const bf16x8*)wbase + wv*6144;   // 96*64 frags per gate
  const bf16x8* whh = (const bf16x8*)smem + wv*2048;
  const int rowA = l & 15, kq = (l >> 4) << 2;
  u32* myc = cnt + 2 + cell;
  const int b_ = tid >> 4, j = tid & 15;
  float creg = 0.f;

  for (int t = 0; t < TT; t++){
    if (t > 0){
      const u32 target = 64u * (u32)t;
      if (tid == 0){
        while (__hip_atomic_load(myc, __ATOMIC_RELAXED, __HIP_MEMORY_SCOPE_AGENT) < target)
          __builtin_amdgcn_s_sleep(2);
        __threadfence();
      }
      __syncthreads();
    }
    f32x4 acc[4] = {{bias,bias,bias,bias},{0,0,0,0},{0,0,0,0},{0,0,0,0}};
    {
      const u16* A0 = h0_all + ((long)t*32 + rowA)*1024;        // h0f
      #pragma unroll
      for (int ks = 0; ks < 32; ks++){
        bf16x8 bf_ = wih[ks*64 + l];
        bf16x8 af  = load_af(A0 + ks*32 + kq);
        acc[ks & 3] = __builtin_amdgcn_mfma_f32_16x16x32_bf16(af, bf_, acc[ks & 3], 0, 0, 0);
      }
      const u16* A1 = h0_all + ((long)t*32 + 16 + rowA)*1024;   // h0b
      #pragma unroll
      for (int ks = 0; ks < 32; ks++){
        bf16x8 bf_ = wih[(32 + ks)*64 + l];
        bf16x8 af  = load_af(A1 + ks*32 + kq);
        acc[ks & 3] = __builtin_amdgcn_mfma_f32_16x16x32_bf16(af, bf_, acc[ks & 3], 0, 0, 0);
      }
    }
    if (t > 0){
      const u16* Ah = h1r + (((long)((t-1)%3)*2 + cell)*16 + rowA)*1024;
      #pragma unroll
      for (int ks = 0; ks < 32; ks++){
        bf16x8 bf_ = whh[ks*64 + l];
        bf16x8 af  = load_af(Ah + ks*32 + kq);
        acc[ks & 3] = __builtin_amdgcn_mfma_f32_16x16x32_bf16(af, bf_, acc[ks & 3], 0, 0, 0);
      }
    }
    f32x4 a = acc[0] + acc[1] + acc[2] + acc[3];
    const int r0 = (l >> 4) << 2, cj = l & 15;
    gl[wv*256 + (r0+0)*16 + cj] = a[0];
    gl[wv*256 + (r0+1)*16 + cj] = a[1];
    gl[wv*256 + (r0+2)*16 + cj] = a[2];
    gl[wv*256 + (r0+3)*16 + cj] = a[3];
    __syncthreads();
    {
      float gi = gl[tid], gf = gl[256 + tid], gg = gl[512 + tid], go = gl[768 + tid];
      float c2 = sigm(gf)*creg + sigm(gi)*tanh_(gg);
      float h2 = sigm(go)*tanh_(c2);
      creg = c2;
      h1r[(((long)(t%3)*2 + cell)*16 + b_)*1024 + jb*16 + j] = f2b(h2);
      out[((long)b_*TT + t)*2048 + cell*1024 + jb*16 + j] = h2;
    }
    __syncthreads();
    if (tid == 0){
      __threadfence();
      __hip_atomic_fetch_add(myc, 1u, __ATOMIC_RELEASE, __HIP_MEMORY_SCOPE_AGENT);
    }
  }
}

extern "C" void kernel_launch(void* const* d_in, const int* in_sizes, int n_in,
                              void* d_out, int out_size, void* d_ws, size_t ws_size,
                              hipStream_t stream){
  const int*   inputs = (const int*)d_in[0];
  const float* emb    = (const float*)d_in[1];
  const float* wih0   = (const float*)d_in[2];
  const float* whh0   = (const float*)d_in[3];
  const float* bih0   = (const float*)d_in[4];
  const float* bhh0   = (const float*)d_in[5];
  const float* wih1   = (const float*)d_in[6];
  const float* whh1   = (const float*)d_in[7];
  const float* bih1   = (const float*)d_in[8];
  const float* bhh1   = (const float*)d_in[9];
  float* out = (float*)d_out;
  char* ws = (char*)d_ws;

  u32*   cnt   = (u32*)(ws + OFS_CNT);
  float* b0    = (float*)(ws + OFS_B0);
  float* b1    = (float*)(ws + OFS_B1);
  u16*   Xb    = (u16*)(ws + OFS_X);
  u16*   Wih0p = (u16*)(ws + OFS_WIH0);
  u16*   Whh0p = (u16*)(ws + OFS_WHH0);
  u16*   W1p   = (u16*)(ws + OFS_W1);
  u16*   h0a   = (u16*)(ws + OFS_H0);
  u16*   h1r   = (u16*)(ws + OFS_H1);

  hipMemsetAsync(cnt, 0, 256, stream);
  k_bias <<<32,   256, 0, stream>>>(bih0, bhh0, bih1, bhh1, b0, b1);
  k_embed<<<8192, 256, 0, stream>>>(inputs, emb, Xb);
  k_pack <<<4096, 256, 0, stream>>>(wih0, (const float*)0, 1024, 0, Wih0p);
  k_pack <<<4096, 256, 0, stream>>>(whh0, (const float*)0, 1024, 0, Whh0p);
  k_pack <<<12288,256, 0, stream>>>(wih1, whh1, 2048, 1024, W1p);

  const int smem_bytes = 131072 + 4096;
  hipFuncSetAttribute(reinterpret_cast<const void*>(&k_l0),
                      hipFuncAttributeMaxDynamicSharedMemorySize, smem_bytes);
  hipFuncSetAttribute(reinterpret_cast<const void*>(&k_l1),
                      hipFuncAttributeMaxDynamicSharedMemorySize, smem_bytes);
  k_l0<<<128, 256, smem_bytes, stream>>>(Wih0p, Whh0p, b0, Xb, h0a, cnt);
  k_l1<<<128, 256, smem_bytes, stream>>>(W1p, b1, h0a, h1r, out, cnt);
}

// Round 2
// 25069.127 us; speedup vs baseline: 1.1089x; 1.1089x over previous
//
#include <hip/hip_runtime.h>
#include <hip/hip_bf16.h>
#include <stdint.h>

// Bidirectional 2-layer LSTM decoder: B=16, T=512, E=H=1024.
// Fused persistent kernel: 256 blocks (1/CU), 512 threads (8 waves, 2/SIMD).
//   blocks 0-127:  layer 0 (cell=dir, jb=16-col tile). Wave pair per gate:
//                  half0 = ih (W in 128 VGPRs, A=X[t]), half1 = hh (W in regs, A=h0[t-1]).
//   blocks 128-255: layer 1. half0 = ih-h0f + hh ks0-15, half1 = ih-h0b + hh ks16-31;
//                  ih weights in regs, hh weights in LDS. Writes d_out + h1 ring.
// Sync: per-group flag array (64 u32), release-store step number, waiter 64-lane
// __all poll. l1 lags l0 by one step -> full overlap.
// k-permutation: A frag elem j <-> k = ks*32 + (lane>>4)*8 + j (contiguous 16B);
// weights packed with the same permutation (MFMA pairs slots positionally).

#define TT 512
#define HH 1024

typedef __bf16 bf16x8 __attribute__((ext_vector_type(8)));
typedef float f32x4 __attribute__((ext_vector_type(4)));
typedef unsigned int u32;
typedef unsigned short u16;

#define MFMA __builtin_amdgcn_mfma_f32_16x16x32_bf16

// ---- workspace layout (bytes) ----
#define OFS_FLAGS 0ul            // [4][64] u32 flags (zeroed each launch)
#define OFS_B0    4096ul         // [2][4096] f32
#define OFS_B1    36864ul        // [2][4096] f32
#define OFS_X     69632ul        // [8192][1024] bf16
#define OFS_WIH0  16846848ul     // packed [2][64][4][32][64][8] bf16
#define OFS_WHH0  33624064ul     // same shape
#define OFS_W1    50401280ul     // packed [2][64][4][96][64][8] bf16 (ih 64ks | hh 32ks)
#define OFS_H0    100732928ul    // [512][2][16][1024] bf16
#define OFS_H1    134287360ul    // [3][2][16][1024] bf16 ring
// end ~134.5 MB

__device__ inline u16 f2b(float f){
  union { float f; u32 u; } x{f};
  return (u16)((x.u + 0x7FFFu + ((x.u >> 16) & 1u)) >> 16);
}
__device__ inline float sigm(float x){ return 1.f/(1.f + __expf(-x)); }
__device__ inline float tanh_(float x){ return 2.f*sigm(2.f*x) - 1.f; }

__device__ inline void wait_ge(const u32* f, u32 tgt, int l){
  while (!__all((int)(__hip_atomic_load(f + l, __ATOMIC_ACQUIRE,
                                        __HIP_MEMORY_SCOPE_AGENT) >= tgt)))
    __builtin_amdgcn_s_sleep(2);
}

__global__ void k_bias(const float* __restrict__ a0, const float* __restrict__ a1,
                       const float* __restrict__ a2, const float* __restrict__ a3,
                       float* __restrict__ b0, float* __restrict__ b1){
  int i = blockIdx.x*256 + threadIdx.x;
  if (i < 8192){ b0[i] = a0[i] + a1[i]; b1[i] = a2[i] + a3[i]; }
}

__global__ void k_embed(const int* __restrict__ inputs, const float* __restrict__ emb,
                        u16* __restrict__ X){
  int row = blockIdx.x;                 // t*16 + b
  int t = row >> 4, b = row & 15;
  int tok = (t == 0) ? 1 : inputs[b*TT + t];   // BOS=1 at t=0
  const float4* src = (const float4*)(emb + (size_t)tok*HH);
  float4 v = src[threadIdx.x];
  ushort4 o = make_ushort4(f2b(v.x), f2b(v.y), f2b(v.z), f2b(v.w));
  ((ushort4*)X)[(size_t)row*256 + threadIdx.x] = o;
}

// pack W[n][k] fp32 -> fragment-major bf16, frag elem j <-> k = ks*32+(l>>4)*8+j
__global__ void k_pack(const float* __restrict__ sA, const float* __restrict__ sB,
                       int KA, int KB, u16* __restrict__ dst){
  int K = KA + KB, KS = K >> 5;
  long idx = (long)blockIdx.x*256 + threadIdx.x;
  long total = 2L*64*4*KS*64;
  if (idx >= total) return;
  int l = (int)(idx & 63);
  long r = idx >> 6;
  int ks = (int)(r % KS); r /= KS;
  int g  = (int)(r & 3);  r >>= 2;
  int jb = (int)(r & 63); r >>= 6;
  int cell = (int)r;
  int n  = g*1024 + jb*16 + (l & 15);
  int k0 = ks*32 + ((l >> 4) << 3);
  const float* s; int kl;
  if (k0 < KA){ s = sA + (long)(cell*4096 + n)*KA; kl = k0; }
  else        { s = sB + (long)(cell*4096 + n)*KB; kl = k0 - KA; }
  float4 f0 = *(const float4*)(s + kl);
  float4 f1 = *(const float4*)(s + kl + 4);
  union { u16 v[8]; int4 q; } o;
  o.v[0]=f2b(f0.x); o.v[1]=f2b(f0.y); o.v[2]=f2b(f0.z); o.v[3]=f2b(f0.w);
  o.v[4]=f2b(f1.x); o.v[5]=f2b(f1.y); o.v[6]=f2b(f1.z); o.v[7]=f2b(f1.w);
  long d = ((((long)cell*64 + jb)*4 + g)*KS + ks)*64 + l;
  ((int4*)dst)[d] = o.q;
}

__global__ __launch_bounds__(512, 2)
void k_fused(const u16* __restrict__ Wih0p, const u16* __restrict__ Whh0p,
             const u16* __restrict__ W1p, const float* __restrict__ b0,
             const float* __restrict__ b1, const u16* __restrict__ Xb,
             u16* h0_all, u16* h1r, float* __restrict__ out, u32* flags)
{
  extern __shared__ char smem[];
  float*  gl   = (float*)smem;                  // [8][256] f32 partial gates
  bf16x8* wlds = (bf16x8*)(smem + 8192);        // l1 hh frags [4][32][64]

  const int tid  = threadIdx.x;
  const int wv   = tid >> 6, l = tid & 63;
  const int gate = wv >> 1, half = wv & 1;
  const int rowA = l & 15;
  const int kq8  = (l >> 4) * 8;                // elem offset within 32-k block
  const int layer = blockIdx.x >> 7;
  const int bid   = blockIdx.x & 127;
  const int cell  = bid >> 6, jb = bid & 63;
  const int b_ = tid >> 4, j = tid & 15;        // epilogue ownership (tid<256)

  // ---- preload weights into registers (and LDS for l1-hh) ----
  bf16x8 w0[32];
  if (layer == 0){
    const u16* base = (half == 0) ? Wih0p : Whh0p;
    const bf16x8* ws = (const bf16x8*)base + ((long)((cell*64+jb)*4 + gate)*32)*64 + l;
    #pragma unroll
    for (int f = 0; f < 32; f++) w0[f] = ws[f*64];
  } else {
    const bf16x8* ws = (const bf16x8*)W1p + ((long)((cell*64+jb)*4 + gate)*96 + half*32)*64 + l;
    #pragma unroll
    for (int f = 0; f < 32; f++) w0[f] = ws[f*64];
    const bf16x8* wb = (const bf16x8*)W1p + (long)((cell*64+jb)*4)*96*64;
    for (int i = tid; i < 8192; i += 512){
      int g = i >> 11, ksl = (i >> 6) & 31, ll = i & 63;
      wlds[i] = wb[((g*96) + 64 + ksl)*64 + ll];
    }
  }
  __syncthreads();

  const float bias = (half == 0)
      ? ((layer == 0 ? b0 : b1)[cell*4096 + gate*1024 + jb*16 + rowA]) : 0.f;
  float creg = 0.f;

  if (layer == 0){
    const u32* flr = flags + cell*64;
    u32* myf = flags + cell*64 + jb;
    for (int t = 0; t < TT; t++){
      f32x4 acc[4] = {{bias,bias,bias,bias},{0,0,0,0},{0,0,0,0},{0,0,0,0}};
      if (half == 0){
        const u16* Ar = Xb + ((long)t*16 + rowA)*1024 + kq8;
        #pragma unroll
        for (int ks = 0; ks < 32; ks++){
          bf16x8 af = *(const bf16x8*)(Ar + ks*32);
          acc[ks & 3] = MFMA(af, w0[ks], acc[ks & 3], 0, 0, 0);
        }
      } else if (t > 0){
        wait_ge(flr, (u32)t, l);
        const u16* Ar = h0_all + (((long)(t-1)*2 + cell)*16 + rowA)*1024 + kq8;
        #pragma unroll
        for (int ks = 0; ks < 32; ks++){
          bf16x8 af = *(const bf16x8*)(Ar + ks*32);
          acc[ks & 3] = MFMA(af, w0[ks], acc[ks & 3], 0, 0, 0);
        }
      }
      f32x4 a = acc[0] + acc[1] + acc[2] + acc[3];
      {
        int r0 = (l >> 4) * 4, cj = l & 15;
        gl[wv*256 + (r0+0)*16 + cj] = a[0];
        gl[wv*256 + (r0+1)*16 + cj] = a[1];
        gl[wv*256 + (r0+2)*16 + cj] = a[2];
        gl[wv*256 + (r0+3)*16 + cj] = a[3];
      }
      __syncthreads();
      if (tid < 256){
        float gi = gl[tid]        + gl[256 + tid];
        float gf = gl[512 + tid]  + gl[768 + tid];
        float gg = gl[1024 + tid] + gl[1280 + tid];
        float go = gl[1536 + tid] + gl[1792 + tid];
        float c2 = sigm(gf)*creg + sigm(gi)*tanh_(gg);
        float h2 = sigm(go)*tanh_(c2);
        creg = c2;
        h0_all[(((long)t*2 + cell)*16 + b_)*1024 + jb*16 + j] = f2b(h2);
      }
      __syncthreads();
      if (tid == 0){
        __threadfence();
        __hip_atomic_store(myf, (u32)(t+1), __ATOMIC_RELEASE, __HIP_MEMORY_SCOPE_AGENT);
      }
    }
  } else {
    const u32* fl0 = flags;
    const u32* fl1 = flags + 64;
    const u32* flo = flags + (2 + cell)*64;
    u32* myf = flags + (2 + cell)*64 + jb;
    const bf16x8* wl = wlds + (gate*32 + half*16)*64 + l;
    for (int t = 0; t < TT; t++){
      wait_ge(fl0, (u32)(t+1), l);            // h0f(t) ready
      wait_ge(fl1, (u32)(t+1), l);            // h0b(t) ready
      if (t > 0) wait_ge(flo, (u32)t, l);     // h1(t-1) ready
      f32x4 acc[4] = {{bias,bias,bias,bias},{0,0,0,0},{0,0,0,0},{0,0,0,0}};
      {
        const u16* Ai = h0_all + (((long)t*2 + half)*16 + rowA)*1024 + kq8;
        #pragma unroll
        for (int ks = 0; ks < 32; ks++){
          bf16x8 af = *(const bf16x8*)(Ai + ks*32);
          acc[ks & 3] = MFMA(af, w0[ks], acc[ks & 3], 0, 0, 0);
        }
      }
      if (t > 0){
        const u16* Ah = h1r + (((long)((t-1)%3)*2 + cell)*16 + rowA)*1024 + half*512 + kq8;
        #pragma unroll
        for (int ks = 0; ks < 16; ks++){
          bf16x8 af  = *(const bf16x8*)(Ah + ks*32);
          bf16x8 bf_ = wl[ks*64];
          acc[ks & 3] = MFMA(af, bf_, acc[ks & 3], 0, 0, 0);
        }
      }
      f32x4 a = acc[0] + acc[1] + acc[2] + acc[3];
      {
        int r0 = (l >> 4) * 4, cj = l & 15;
        gl[wv*256 + (r0+0)*16 + cj] = a[0];
        gl[wv*256 + (r0+1)*16 + cj] = a[1];
        gl[wv*256 + (r0+2)*16 + cj] = a[2];
        gl[wv*256 + (r0+3)*16 + cj] = a[3];
      }
      __syncthreads();
      if (tid < 256){
        float gi = gl[tid]        + gl[256 + tid];
        float gf = gl[512 + tid]  + gl[768 + tid];
        float gg = gl[1024 + tid] + gl[1280 + tid];
        float go = gl[1536 + tid] + gl[1792 + tid];
        float c2 = sigm(gf)*creg + sigm(gi)*tanh_(gg);
        float h2 = sigm(go)*tanh_(c2);
        creg = c2;
        h1r[(((long)(t%3)*2 + cell)*16 + b_)*1024 + jb*16 + j] = f2b(h2);
        out[((long)b_*TT + t)*2048 + cell*1024 + jb*16 + j] = h2;
      }
      __syncthreads();
      if (tid == 0){
        __threadfence();
        __hip_atomic_store(myf, (u32)(t+1), __ATOMIC_RELEASE, __HIP_MEMORY_SCOPE_AGENT);
      }
    }
  }
}

extern "C" void kernel_launch(void* const* d_in, const int* in_sizes, int n_in,
                              void* d_out, int out_size, void* d_ws, size_t ws_size,
                              hipStream_t stream){
  const int*   inputs = (const int*)d_in[0];
  const float* emb    = (const float*)d_in[1];
  const float* wih0   = (const float*)d_in[2];
  const float* whh0   = (const float*)d_in[3];
  const float* bih0   = (const float*)d_in[4];
  const float* bhh0   = (const float*)d_in[5];
  const float* wih1   = (const float*)d_in[6];
  const float* whh1   = (const float*)d_in[7];
  const float* bih1   = (const float*)d_in[8];
  const float* bhh1   = (const float*)d_in[9];
  float* out = (float*)d_out;
  char* ws = (char*)d_ws;

  u32*   flags = (u32*)(ws + OFS_FLAGS);
  float* b0    = (float*)(ws + OFS_B0);
  float* b1    = (float*)(ws + OFS_B1);
  u16*   Xb    = (u16*)(ws + OFS_X);
  u16*   Wih0p = (u16*)(ws + OFS_WIH0);
  u16*   Whh0p = (u16*)(ws + OFS_WHH0);
  u16*   W1p   = (u16*)(ws + OFS_W1);
  u16*   h0a   = (u16*)(ws + OFS_H0);
  u16*   h1r   = (u16*)(ws + OFS_H1);

  hipMemsetAsync(flags, 0, 4096, stream);
  k_bias <<<32,   256, 0, stream>>>(bih0, bhh0, bih1, bhh1, b0, b1);
  k_embed<<<8192, 256, 0, stream>>>(inputs, emb, Xb);
  k_pack <<<4096, 256, 0, stream>>>(wih0, (const float*)0, 1024, 0, Wih0p);
  k_pack <<<4096, 256, 0, stream>>>(whh0, (const float*)0, 1024, 0, Whh0p);
  k_pack <<<12288,256, 0, stream>>>(wih1, whh1, 2048, 1024, W1p);

  const int smem_bytes = 139264;   // 8KB gate buffer + 128KB l1-hh frags
  hipFuncSetAttribute(reinterpret_cast<const void*>(&k_fused),
                      hipFuncAttributeMaxDynamicSharedMemorySize, smem_bytes);
  k_fused<<<256, 512, smem_bytes, stream>>>(Wih0p, Whh0p, W1p, b0, b1, Xb,
                                            h0a, h1r, out, flags);
}

// Round 3
// 12603.622 us; speedup vs baseline: 2.2057x; 1.9890x over previous
//
#include <hip/hip_runtime.h>
#include <hip/hip_bf16.h>
#include <stdint.h>

// Bidirectional 2-layer LSTM decoder: B=16, T=512, E=H=1024.
// Fused persistent kernel, 256 blocks (1/CU), 512 threads (8 waves).
// Key properties this round:
//  - Weights truly VGPR-resident: preload then asm "+v" opacity pin (prevents
//    LLVM from sinking the loads back into the t-loop; round-2 VGPR=104 proved
//    it had done exactly that).
//  - Zero fences on the critical path: all cross-block state (h0/h1/flags)
//    uses relaxed AGENT-scope atomics (sc1 read/write-through to the die-level
//    coherence point). Producer: sc1 stores -> per-wave s_waitcnt vmcnt(0) ->
//    relaxed flag store. Consumer: relaxed flag poll -> sc1 data loads.
//    No __threadfence => no buffer_wbl2 L2 walks per step.
//  - Wave map: half = wv>>2 (0=ih background, 1=hh critical) so each SIMD has
//    one critical and one background wave.

#define TT 512
#define HH 1024

typedef __bf16 bf16x8 __attribute__((ext_vector_type(8)));
typedef float f32x4 __attribute__((ext_vector_type(4)));
typedef unsigned int u32;
typedef unsigned short u16;
typedef unsigned long long u64;

#define MFMA __builtin_amdgcn_mfma_f32_16x16x32_bf16

// ---- workspace layout (bytes) ----
#define OFS_FLAGS 0ul            // [4][64] u32 flags (zeroed each launch)
#define OFS_B0    4096ul         // [2][4096] f32
#define OFS_B1    36864ul        // [2][4096] f32
#define OFS_X     69632ul        // [8192][1024] bf16
#define OFS_WIH0  16846848ul     // packed [2][64][4][32][64][8] bf16
#define OFS_WHH0  33624064ul     // same shape
#define OFS_W1    50401280ul     // packed [2][64][4][96][64][8] bf16 (ih 64ks | hh 32ks)
#define OFS_H0    100732928ul    // [512][2][16][1024] bf16
#define OFS_H1    134287360ul    // [3][2][16][1024] bf16 ring
// end ~134.5 MB

__device__ inline u16 f2b(float f){
  union { float f; u32 u; } x{f};
  return (u16)((x.u + 0x7FFFu + ((x.u >> 16) & 1u)) >> 16);
}
__device__ inline float sigm(float x){ return 1.f/(1.f + __expf(-x)); }
__device__ inline float tanh_(float x){ return 2.f*sigm(2.f*x) - 1.f; }

// relaxed agent-scope (device-coherent, fence-free) ops
__device__ inline u32 ldf(const u32* p){
  return __hip_atomic_load(p, __ATOMIC_RELAXED, __HIP_MEMORY_SCOPE_AGENT);
}
__device__ inline void stf(u32* p, u32 v){
  __hip_atomic_store(p, v, __ATOMIC_RELAXED, __HIP_MEMORY_SCOPE_AGENT);
}
__device__ inline bf16x8 ldc(const u16* p){
  union { u64 d[2]; bf16x8 v; } r;
  const u64* q = (const u64*)p;
  r.d[0] = __hip_atomic_load(q,     __ATOMIC_RELAXED, __HIP_MEMORY_SCOPE_AGENT);
  r.d[1] = __hip_atomic_load(q + 1, __ATOMIC_RELAXED, __HIP_MEMORY_SCOPE_AGENT);
  return r.v;
}

__global__ void k_bias(const float* __restrict__ a0, const float* __restrict__ a1,
                       const float* __restrict__ a2, const float* __restrict__ a3,
                       float* __restrict__ b0, float* __restrict__ b1){
  int i = blockIdx.x*256 + threadIdx.x;
  if (i < 8192){ b0[i] = a0[i] + a1[i]; b1[i] = a2[i] + a3[i]; }
}

__global__ void k_embed(const int* __restrict__ inputs, const float* __restrict__ emb,
                        u16* __restrict__ X){
  int row = blockIdx.x;                 // t*16 + b
  int t = row >> 4, b = row & 15;
  int tok = (t == 0) ? 1 : inputs[b*TT + t];   // BOS=1 at t=0
  const float4* src = (const float4*)(emb + (size_t)tok*HH);
  float4 v = src[threadIdx.x];
  ushort4 o = make_ushort4(f2b(v.x), f2b(v.y), f2b(v.z), f2b(v.w));
  ((ushort4*)X)[(size_t)row*256 + threadIdx.x] = o;
}

// pack W[n][k] fp32 -> fragment-major bf16, frag elem j <-> k = ks*32+(l>>4)*8+j
__global__ void k_pack(const float* __restrict__ sA, const float* __restrict__ sB,
                       int KA, int KB, u16* __restrict__ dst){
  int K = KA + KB, KS = K >> 5;
  long idx = (long)blockIdx.x*256 + threadIdx.x;
  long total = 2L*64*4*KS*64;
  if (idx >= total) return;
  int l = (int)(idx & 63);
  long r = idx >> 6;
  int ks = (int)(r % KS); r /= KS;
  int g  = (int)(r & 3);  r >>= 2;
  int jb = (int)(r & 63); r >>= 6;
  int cell = (int)r;
  int n  = g*1024 + jb*16 + (l & 15);
  int k0 = ks*32 + ((l >> 4) << 3);
  const float* s; int kl;
  if (k0 < KA){ s = sA + (long)(cell*4096 + n)*KA; kl = k0; }
  else        { s = sB + (long)(cell*4096 + n)*KB; kl = k0 - KA; }
  float4 f0 = *(const float4*)(s + kl);
  float4 f1 = *(const float4*)(s + kl + 4);
  union { u16 v[8]; int4 q; } o;
  o.v[0]=f2b(f0.x); o.v[1]=f2b(f0.y); o.v[2]=f2b(f0.z); o.v[3]=f2b(f0.w);
  o.v[4]=f2b(f1.x); o.v[5]=f2b(f1.y); o.v[6]=f2b(f1.z); o.v[7]=f2b(f1.w);
  long d = ((((long)cell*64 + jb)*4 + g)*KS + ks)*64 + l;
  ((int4*)dst)[d] = o.q;
}

__global__ __launch_bounds__(512, 2)
void k_fused(const u16* __restrict__ Wih0p, const u16* __restrict__ Whh0p,
             const u16* __restrict__ W1p, const float* __restrict__ b0,
             const float* __restrict__ b1, const u16* __restrict__ Xb,
             u16* h0_all, u16* h1r, float* __restrict__ out, u32* flags)
{
  extern __shared__ char smem[];
  float*  gl   = (float*)smem;                  // [8][256] f32 partial gates
  bf16x8* wlds = (bf16x8*)(smem + 8192);        // l1 hh frags [4][32][64]

  const int tid  = threadIdx.x;
  const int wv   = tid >> 6, l = tid & 63;
  const int half = wv >> 2, gate = wv & 3;      // half0: ih (waves 0-3), half1: hh/second-ih
  const int rowA = l & 15;
  const int kq8  = (l >> 4) * 8;
  const int layer = blockIdx.x >> 7;
  const int bid   = blockIdx.x & 127;
  const int cell  = bid >> 6, jb = bid & 63;
  const int b_ = tid >> 4, j = tid & 15;

  // ---- preload weights into registers (and LDS for l1-hh) ----
  f32x4 w0[32];
  if (layer == 0){
    const u16* base = (half == 0) ? Wih0p : Whh0p;
    const f32x4* ws = (const f32x4*)base + ((long)((cell*64+jb)*4 + gate)*32)*64 + l;
    #pragma unroll
    for (int f = 0; f < 32; f++) w0[f] = ws[f*64];
  } else {
    const f32x4* ws = (const f32x4*)W1p + ((long)((cell*64+jb)*4 + gate)*96 + half*32)*64 + l;
    #pragma unroll
    for (int f = 0; f < 32; f++) w0[f] = ws[f*64];
    const f32x4* wb = (const f32x4*)W1p + (long)((cell*64+jb)*4)*96*64;
    for (int i = tid; i < 8192; i += 512){
      int g = i >> 11, ksl = (i >> 6) & 31, ll = i & 63;
      ((f32x4*)wlds)[i] = wb[((g*96) + 64 + ksl)*64 + ll];
    }
  }
  // Pin: make weight values opaque so LLVM cannot re-load them inside the loop.
  #pragma unroll
  for (int f = 0; f < 32; f++) asm volatile("" : "+v"(w0[f]));
  __syncthreads();

  const float bias = (half == 0)
      ? ((layer == 0 ? b0 : b1)[cell*4096 + gate*1024 + jb*16 + rowA]) : 0.f;
  float creg = 0.f;

  if (layer == 0){
    const u32* flr = flags + cell*64;
    u32* myf = flags + cell*64 + jb;
    u32* hdst = (u32*)h0_all;
    for (int t = 0; t < TT; t++){
      f32x4 acc[4] = {{bias,bias,bias,bias},{0,0,0,0},{0,0,0,0},{0,0,0,0}};
      if (half == 0){
        const u16* Ar = Xb + ((long)t*16 + rowA)*1024 + kq8;
        #pragma unroll
        for (int ks = 0; ks < 32; ks++)
          acc[ks & 3] = MFMA(*(const bf16x8*)(Ar + ks*32),
                             __builtin_bit_cast(bf16x8, w0[ks]), acc[ks & 3], 0, 0, 0);
      } else if (t > 0){
        while (!__all((int)(ldf(flr + l) >= (u32)t))) __builtin_amdgcn_s_sleep(4);
        const u16* Ar = h0_all + (((long)(t-1)*2 + cell)*16 + rowA)*1024 + kq8;
        #pragma unroll
        for (int ks = 0; ks < 32; ks++)
          acc[ks & 3] = MFMA(ldc(Ar + ks*32),
                             __builtin_bit_cast(bf16x8, w0[ks]), acc[ks & 3], 0, 0, 0);
      }
      f32x4 a = acc[0] + acc[1] + acc[2] + acc[3];
      {
        int r0 = (l >> 4) * 4, cj = l & 15;
        gl[wv*256 + (r0+0)*16 + cj] = a[0];
        gl[wv*256 + (r0+1)*16 + cj] = a[1];
        gl[wv*256 + (r0+2)*16 + cj] = a[2];
        gl[wv*256 + (r0+3)*16 + cj] = a[3];
      }
      __syncthreads();
      if (tid < 256){
        float gi = gl[tid]        + gl[1024 + tid];
        float gf = gl[256 + tid]  + gl[1280 + tid];
        float gg = gl[512 + tid]  + gl[1536 + tid];
        float go = gl[768 + tid]  + gl[1792 + tid];
        float c2 = sigm(gf)*creg + sigm(gi)*tanh_(gg);
        float h2 = sigm(go)*tanh_(c2);
        creg = c2;
        u32 lo = f2b(h2);
        u32 hi = __shfl_down(lo, 1);
        if (!(tid & 1)){
          long idx = ((((long)t*2 + cell)*16 + b_)*1024 + jb*16 + j) >> 1;
          stf(hdst + idx, lo | (hi << 16));
        }
        asm volatile("s_waitcnt vmcnt(0)" ::: "memory");  // per-wave drain of sc1 stores
      }
      __syncthreads();
      if (tid == 0) stf(myf, (u32)(t+1));
    }
  } else {
    const u32* fl0 = flags;
    const u32* fl1 = flags + 64;
    const u32* flo = flags + (2 + cell)*64;
    u32* myf = flags + (2 + cell)*64 + jb;
    const bf16x8* wl = wlds + (gate*32 + half*16)*64 + l;
    u32* hdst = (u32*)h1r;
    for (int t = 0; t < TT; t++){
      {
        const u32 tgt = (u32)(t + 1);
        for (;;){
          int ok = (ldf(fl0 + l) >= tgt) && (ldf(fl1 + l) >= tgt)
                   && (t == 0 || ldf(flo + l) >= (u32)t);
          if (__all(ok)) break;
          __builtin_amdgcn_s_sleep(4);
        }
      }
      f32x4 acc[4] = {{bias,bias,bias,bias},{0,0,0,0},{0,0,0,0},{0,0,0,0}};
      {
        const u16* Ai = h0_all + (((long)t*2 + half)*16 + rowA)*1024 + kq8;
        #pragma unroll
        for (int ks = 0; ks < 32; ks++)
          acc[ks & 3] = MFMA(ldc(Ai + ks*32),
                             __builtin_bit_cast(bf16x8, w0[ks]), acc[ks & 3], 0, 0, 0);
      }
      if (t > 0){
        const u16* Ah = h1r + (((long)((t-1)%3)*2 + cell)*16 + rowA)*1024 + half*512 + kq8;
        #pragma unroll
        for (int ks = 0; ks < 16; ks++)
          acc[ks & 3] = MFMA(ldc(Ah + ks*32), wl[ks*64], acc[ks & 3], 0, 0, 0);
      }
      f32x4 a = acc[0] + acc[1] + acc[2] + acc[3];
      {
        int r0 = (l >> 4) * 4, cj = l & 15;
        gl[wv*256 + (r0+0)*16 + cj] = a[0];
        gl[wv*256 + (r0+1)*16 + cj] = a[1];
        gl[wv*256 + (r0+2)*16 + cj] = a[2];
        gl[wv*256 + (r0+3)*16 + cj] = a[3];
      }
      __syncthreads();
      if (tid < 256){
        float gi = gl[tid]        + gl[1024 + tid];
        float gf = gl[256 + tid]  + gl[1280 + tid];
        float gg = gl[512 + tid]  + gl[1536 + tid];
        float go = gl[768 + tid]  + gl[1792 + tid];
        float c2 = sigm(gf)*creg + sigm(gi)*tanh_(gg);
        float h2 = sigm(go)*tanh_(c2);
        creg = c2;
        out[((long)b_*TT + t)*2048 + cell*1024 + jb*16 + j] = h2;
        u32 lo = f2b(h2);
        u32 hi = __shfl_down(lo, 1);
        if (!(tid & 1)){
          long idx = ((((long)(t%3)*2 + cell)*16 + b_)*1024 + jb*16 + j) >> 1;
          stf(hdst + idx, lo | (hi << 16));
        }
        asm volatile("s_waitcnt vmcnt(0)" ::: "memory");
      }
      __syncthreads();
      if (tid == 0) stf(myf, (u32)(t+1));
    }
  }
}

extern "C" void kernel_launch(void* const* d_in, const int* in_sizes, int n_in,
                              void* d_out, int out_size, void* d_ws, size_t ws_size,
                              hipStream_t stream){
  const int*   inputs = (const int*)d_in[0];
  const float* emb    = (const float*)d_in[1];
  const float* wih0   = (const float*)d_in[2];
  const float* whh0   = (const float*)d_in[3];
  const float* bih0   = (const float*)d_in[4];
  const float* bhh0   = (const float*)d_in[5];
  const float* wih1   = (const float*)d_in[6];
  const float* whh1   = (const float*)d_in[7];
  const float* bih1   = (const float*)d_in[8];
  const float* bhh1   = (const float*)d_in[9];
  float* out = (float*)d_out;
  char* ws = (char*)d_ws;

  u32*   flags = (u32*)(ws + OFS_FLAGS);
  float* b0    = (float*)(ws + OFS_B0);
  float* b1    = (float*)(ws + OFS_B1);
  u16*   Xb    = (u16*)(ws + OFS_X);
  u16*   Wih0p = (u16*)(ws + OFS_WIH0);
  u16*   Whh0p = (u16*)(ws + OFS_WHH0);
  u16*   W1p   = (u16*)(ws + OFS_W1);
  u16*   h0a   = (u16*)(ws + OFS_H0);
  u16*   h1r   = (u16*)(ws + OFS_H1);

  hipMemsetAsync(flags, 0, 4096, stream);
  k_bias <<<32,   256, 0, stream>>>(bih0, bhh0, bih1, bhh1, b0, b1);
  k_embed<<<8192, 256, 0, stream>>>(inputs, emb, Xb);
  k_pack <<<4096, 256, 0, stream>>>(wih0, (const float*)0, 1024, 0, Wih0p);
  k_pack <<<4096, 256, 0, stream>>>(whh0, (const float*)0, 1024, 0, Whh0p);
  k_pack <<<12288,256, 0, stream>>>(wih1, whh1, 2048, 1024, W1p);

  const int smem_bytes = 139264;   // 8KB gate buffer + 128KB l1-hh frags
  hipFuncSetAttribute(reinterpret_cast<const void*>(&k_fused),
                      hipFuncAttributeMaxDynamicSharedMemorySize, smem_bytes);
  k_fused<<<256, 512, smem_bytes, stream>>>(Wih0p, Whh0p, W1p, b0, b1, Xb,
                                            h0a, h1r, out, flags);
}

// Round 4
// 5688.227 us; speedup vs baseline: 4.8873x; 2.2157x over previous
//
#include <hip/hip_runtime.h>
#include <hip/hip_bf16.h>
#include <stdint.h>

// Bidirectional 2-layer LSTM decoder: B=16, T=512, E=H=1024.
// Round-4 structure: 256 blocks x 256 threads (4 waves, 1 wave/SIMD).
//  - K-split waves: each wave owns a K-slice for ALL 4 gates.
//    l0: K=2048 (ih 0-31 | hh 32-63 ks), wave w -> ks w*16..w*16+15. 64 VGPR-frag weights.
//    l1: K=3072 (h0f 0-31 | h0b 32-63 | h1 64-95 ks), wave w -> ks w*24..+23. 96 frags (384 VGPR).
//    => every A fragment loaded exactly ONCE per block (was 4-8x redundant sc1 MALL reads).
//  - Single polling wave (wave 3) + barrier release: 64x less flag-poll traffic, no sleep.
//  - Weights pinned in regs via asm "+v"; launch_bounds(256,1) allows up to 512 VGPR.
//  - h1 ring slot 2 pre-zeroed => l1 t=0 needs no special case (h1(-1)=0 exactly).
//  - Cross-block data/flags via relaxed agent-scope (sc1) ops; producer drains vmcnt
//    before barrier, tid0 stores flag after barrier. No fences anywhere in the loop.

#define TT 512
#define HH 1024

typedef __bf16 bf16x8 __attribute__((ext_vector_type(8)));
typedef float f32x4 __attribute__((ext_vector_type(4)));
typedef unsigned int u32;
typedef unsigned short u16;
typedef unsigned long long u64;

#define MFMA __builtin_amdgcn_mfma_f32_16x16x32_bf16

// ---- workspace layout (bytes) ----
#define OFS_FLAGS 0ul            // [4][64] u32 flags (zeroed each launch)
#define OFS_B0    4096ul         // [2][4096] f32
#define OFS_B1    36864ul        // [2][4096] f32
#define OFS_X     69632ul        // [8192][1024] bf16
#define OFS_WIH0  16846848ul     // packed [2][64][4][32][64][8] bf16
#define OFS_WHH0  33624064ul     // same shape
#define OFS_W1    50401280ul     // packed [2][64][4][96][64][8] bf16 (ih 64ks | hh 32ks)
#define OFS_H0    100732928ul    // [512][2][16][1024] bf16
#define OFS_H1    134287360ul    // [3][2][16][1024] bf16 ring
// end ~134.5 MB

__device__ inline u16 f2b(float f){
  union { float f; u32 u; } x{f};
  return (u16)((x.u + 0x7FFFu + ((x.u >> 16) & 1u)) >> 16);
}
__device__ inline float sigm(float x){ return 1.f/(1.f + __expf(-x)); }
__device__ inline float tanh_(float x){ return 2.f*sigm(2.f*x) - 1.f; }

// relaxed agent-scope (device-coherent, fence-free) ops
__device__ inline u32 ldf(const u32* p){
  return __hip_atomic_load(p, __ATOMIC_RELAXED, __HIP_MEMORY_SCOPE_AGENT);
}
__device__ inline void stf(u32* p, u32 v){
  __hip_atomic_store(p, v, __ATOMIC_RELAXED, __HIP_MEMORY_SCOPE_AGENT);
}
__device__ inline bf16x8 ldc(const u16* p){
  union { u64 d[2]; bf16x8 v; } r;
  const u64* q = (const u64*)p;
  r.d[0] = __hip_atomic_load(q,     __ATOMIC_RELAXED, __HIP_MEMORY_SCOPE_AGENT);
  r.d[1] = __hip_atomic_load(q + 1, __ATOMIC_RELAXED, __HIP_MEMORY_SCOPE_AGENT);
  return r.v;
}

__global__ void k_bias(const float* __restrict__ a0, const float* __restrict__ a1,
                       const float* __restrict__ a2, const float* __restrict__ a3,
                       float* __restrict__ b0, float* __restrict__ b1,
                       u64* __restrict__ h1z){
  int i = blockIdx.x*256 + threadIdx.x;
  if (i < 8192){ b0[i] = a0[i] + a1[i]; b1[i] = a2[i] + a3[i]; h1z[i] = 0ull; }
}

__global__ void k_embed(const int* __restrict__ inputs, const float* __restrict__ emb,
                        u16* __restrict__ X){
  int row = blockIdx.x;                 // t*16 + b
  int t = row >> 4, b = row & 15;
  int tok = (t == 0) ? 1 : inputs[b*TT + t];   // BOS=1 at t=0
  const float4* src = (const float4*)(emb + (size_t)tok*HH);
  float4 v = src[threadIdx.x];
  ushort4 o = make_ushort4(f2b(v.x), f2b(v.y), f2b(v.z), f2b(v.w));
  ((ushort4*)X)[(size_t)row*256 + threadIdx.x] = o;
}

// pack W[n][k] fp32 -> fragment-major bf16, frag elem j <-> k = ks*32+(l>>4)*8+j
__global__ void k_pack(const float* __restrict__ sA, const float* __restrict__ sB,
                       int KA, int KB, u16* __restrict__ dst){
  int K = KA + KB, KS = K >> 5;
  long idx = (long)blockIdx.x*256 + threadIdx.x;
  long total = 2L*64*4*KS*64;
  if (idx >= total) return;
  int l = (int)(idx & 63);
  long r = idx >> 6;
  int ks = (int)(r % KS); r /= KS;
  int g  = (int)(r & 3);  r >>= 2;
  int jb = (int)(r & 63); r >>= 6;
  int cell = (int)r;
  int n  = g*1024 + jb*16 + (l & 15);
  int k0 = ks*32 + ((l >> 4) << 3);
  const float* s; int kl;
  if (k0 < KA){ s = sA + (long)(cell*4096 + n)*KA; kl = k0; }
  else        { s = sB + (long)(cell*4096 + n)*KB; kl = k0 - KA; }
  float4 f0 = *(const float4*)(s + kl);
  float4 f1 = *(const float4*)(s + kl + 4);
  union { u16 v[8]; int4 q; } o;
  o.v[0]=f2b(f0.x); o.v[1]=f2b(f0.y); o.v[2]=f2b(f0.z); o.v[3]=f2b(f0.w);
  o.v[4]=f2b(f1.x); o.v[5]=f2b(f1.y); o.v[6]=f2b(f1.z); o.v[7]=f2b(f1.w);
  long d = ((((long)cell*64 + jb)*4 + g)*KS + ks)*64 + l;
  ((int4*)dst)[d] = o.q;
}

__global__ __launch_bounds__(256, 1)
void k_fused(const u16* __restrict__ Wih0p, const u16* __restrict__ Whh0p,
             const u16* __restrict__ W1p, const float* __restrict__ b0,
             const float* __restrict__ b1, const u16* __restrict__ Xb,
             u16* h0_all, u16* h1r, float* __restrict__ out, u32* flags)
{
  __shared__ float gl[4096];                    // [wave][gate][256] partials

  const int tid  = threadIdx.x;
  const int wv   = tid >> 6, l = tid & 63;
  const int rowA = l & 15;
  const int kq8  = (l >> 4) * 8;
  const int layer = blockIdx.x >> 7;
  const int bid   = blockIdx.x & 127;
  const int cell  = bid >> 6, jb = bid & 63;
  const int b_ = tid >> 4, j = tid & 15;

  float bias[4];
  {
    const float* bb = (layer == 0 ? b0 : b1) + cell*4096 + jb*16 + rowA;
    #pragma unroll
    for (int g = 0; g < 4; g++) bias[g] = (wv == 0) ? bb[g*1024] : 0.f;
  }
  float creg = 0.f;

  if (layer == 0){
    // ---- weights: wave w covers global ks w*16..w*16+15 of [ih 0-31 | hh 32-63] ----
    f32x4 w[4][16];
    {
      const f32x4* src = (const f32x4*)(wv < 2 ? Wih0p : Whh0p)
                       + ((long)(cell*64 + jb)*4)*32*64 + l;
      #pragma unroll
      for (int g = 0; g < 4; g++){
        #pragma unroll
        for (int i = 0; i < 16; i++){
          int ksl = (wv*16 + i) & 31;
          w[g][i] = src[((long)g*32 + ksl)*64];
        }
      }
    }
    #pragma unroll
    for (int g = 0; g < 4; g++){
      #pragma unroll
      for (int i = 0; i < 16; i++) asm volatile("" : "+v"(w[g][i]));
    }

    const u32* flr = flags + cell*64;
    u32* myf = flags + cell*64 + jb;
    u32* hdst = (u32*)h0_all;
    const int ko = (wv & 1) * 16;               // ks offset within source matrix

    for (int t = 0; t < TT; t++){
      if (wv == 3 && t > 0){
        while (!__all((int)(ldf(flr + l) >= (u32)t))) {}
      }
      __syncthreads();
      f32x4 acc[4];
      #pragma unroll
      for (int g = 0; g < 4; g++) acc[g] = (f32x4){bias[g],bias[g],bias[g],bias[g]};
      if (wv < 2){
        const u16* A = Xb + ((long)t*16 + rowA)*1024 + kq8 + ko*32;
        #pragma unroll
        for (int i = 0; i < 16; i++){
          bf16x8 af = *(const bf16x8*)(A + i*32);
          #pragma unroll
          for (int g = 0; g < 4; g++)
            acc[g] = MFMA(af, __builtin_bit_cast(bf16x8, w[g][i]), acc[g], 0, 0, 0);
        }
      } else if (t > 0){
        const u16* A = h0_all + (((long)(t-1)*2 + cell)*16 + rowA)*1024 + kq8 + ko*32;
        #pragma unroll
        for (int i = 0; i < 16; i++){
          bf16x8 af = ldc(A + i*32);
          #pragma unroll
          for (int g = 0; g < 4; g++)
            acc[g] = MFMA(af, __builtin_bit_cast(bf16x8, w[g][i]), acc[g], 0, 0, 0);
        }
      }
      {
        int r0 = (l >> 4)*4, cj = l & 15;
        #pragma unroll
        for (int g = 0; g < 4; g++){
          #pragma unroll
          for (int i2 = 0; i2 < 4; i2++)
            gl[wv*1024 + g*256 + (r0+i2)*16 + cj] = acc[g][i2];
        }
      }
      __syncthreads();
      {
        float gi = gl[tid]      + gl[1024+tid] + gl[2048+tid] + gl[3072+tid];
        float gf = gl[256+tid]  + gl[1280+tid] + gl[2304+tid] + gl[3328+tid];
        float gg = gl[512+tid]  + gl[1536+tid] + gl[2560+tid] + gl[3584+tid];
        float go = gl[768+tid]  + gl[1792+tid] + gl[2816+tid] + gl[3840+tid];
        float c2 = sigm(gf)*creg + sigm(gi)*tanh_(gg);
        float h2 = sigm(go)*tanh_(c2);
        creg = c2;
        u32 lo = f2b(h2), hi = __shfl_down(lo, 1);
        if (!(tid & 1)){
          long idx = ((((long)t*2 + cell)*16 + b_)*1024 + jb*16 + j) >> 1;
          stf(hdst + idx, lo | (hi << 16));
        }
        asm volatile("s_waitcnt vmcnt(0)" ::: "memory");
      }
      __syncthreads();
      if (tid == 0) stf(myf, (u32)(t+1));
    }
  } else {
    // ---- layer 1: wave w covers global ks w*24..w*24+23 of [h0f|h0b|h1] ----
    f32x4 w[4][24];
    {
      const f32x4* src = (const f32x4*)W1p + ((long)(cell*64 + jb)*4)*96*64 + l;
      #pragma unroll
      for (int g = 0; g < 4; g++){
        #pragma unroll
        for (int i = 0; i < 24; i++)
          w[g][i] = src[((long)g*96 + wv*24 + i)*64];
      }
    }
    #pragma unroll
    for (int g = 0; g < 4; g++){
      #pragma unroll
      for (int i = 0; i < 24; i++) asm volatile("" : "+v"(w[g][i]));
    }

    const u32* fl0 = flags;
    const u32* fl1 = flags + 64;
    const u32* flo = flags + (2 + cell)*64;
    u32* myf = flags + (2 + cell)*64 + jb;
    u32* hdst = (u32*)h1r;
    int tm = 2, ts = 0;                         // (t+2)%3 read slot, t%3 write slot

    for (int t = 0; t < TT; t++){
      if (wv == 3){
        const u32 tgt = (u32)(t + 1);
        for (;;){
          int ok = (ldf(fl0 + l) >= tgt) && (ldf(fl1 + l) >= tgt)
                   && (ldf(flo + l) >= (u32)t);
          if (__all(ok)) break;
        }
      }
      __syncthreads();
      f32x4 acc[4];
      #pragma unroll
      for (int g = 0; g < 4; g++) acc[g] = (f32x4){bias[g],bias[g],bias[g],bias[g]};
      {
        const u16* bA = h0_all + ((long)t*32 + rowA)*1024 + kq8;        // h0f
        const u16* bB = bA + 16*1024;                                    // h0b
        const u16* bC = h1r + (((long)tm*2 + cell)*16 + rowA)*1024 + kq8;// h1(t-1)
        #pragma unroll
        for (int i = 0; i < 24; i++){
          int gk = wv*24 + i;
          int r = gk >> 5, ksl = gk & 31;
          const u16* p = (r == 0) ? bA : (r == 1) ? bB : bC;
          bf16x8 af = ldc(p + ksl*32);
          #pragma unroll
          for (int g = 0; g < 4; g++)
            acc[g] = MFMA(af, __builtin_bit_cast(bf16x8, w[g][i]), acc[g], 0, 0, 0);
        }
      }
      {
        int r0 = (l >> 4)*4, cj = l & 15;
        #pragma unroll
        for (int g = 0; g < 4; g++){
          #pragma unroll
          for (int i2 = 0; i2 < 4; i2++)
            gl[wv*1024 + g*256 + (r0+i2)*16 + cj] = acc[g][i2];
        }
      }
      __syncthreads();
      {
        float gi = gl[tid]      + gl[1024+tid] + gl[2048+tid] + gl[3072+tid];
        float gf = gl[256+tid]  + gl[1280+tid] + gl[2304+tid] + gl[3328+tid];
        float gg = gl[512+tid]  + gl[1536+tid] + gl[2560+tid] + gl[3584+tid];
        float go = gl[768+tid]  + gl[1792+tid] + gl[2816+tid] + gl[3840+tid];
        float c2 = sigm(gf)*creg + sigm(gi)*tanh_(gg);
        float h2 = sigm(go)*tanh_(c2);
        creg = c2;
        out[((long)b_*TT + t)*2048 + cell*1024 + jb*16 + j] = h2;
        u32 lo = f2b(h2), hi = __shfl_down(lo, 1);
        if (!(tid & 1)){
          long idx = ((((long)ts*2 + cell)*16 + b_)*1024 + jb*16 + j) >> 1;
          stf(hdst + idx, lo | (hi << 16));
        }
        asm volatile("s_waitcnt vmcnt(0)" ::: "memory");
      }
      __syncthreads();
      if (tid == 0) stf(myf, (u32)(t+1));
      tm = (tm == 2) ? 0 : tm + 1;
      ts = (ts == 2) ? 0 : ts + 1;
    }
  }
}

extern "C" void kernel_launch(void* const* d_in, const int* in_sizes, int n_in,
                              void* d_out, int out_size, void* d_ws, size_t ws_size,
                              hipStream_t stream){
  const int*   inputs = (const int*)d_in[0];
  const float* emb    = (const float*)d_in[1];
  const float* wih0   = (const float*)d_in[2];
  const float* whh0   = (const float*)d_in[3];
  const float* bih0   = (const float*)d_in[4];
  const float* bhh0   = (const float*)d_in[5];
  const float* wih1   = (const float*)d_in[6];
  const float* whh1   = (const float*)d_in[7];
  const float* bih1   = (const float*)d_in[8];
  const float* bhh1   = (const float*)d_in[9];
  float* out = (float*)d_out;
  char* ws = (char*)d_ws;

  u32*   flags = (u32*)(ws + OFS_FLAGS);
  float* b0    = (float*)(ws + OFS_B0);
  float* b1    = (float*)(ws + OFS_B1);
  u16*   Xb    = (u16*)(ws + OFS_X);
  u16*   Wih0p = (u16*)(ws + OFS_WIH0);
  u16*   Whh0p = (u16*)(ws + OFS_WHH0);
  u16*   W1p   = (u16*)(ws + OFS_W1);
  u16*   h0a   = (u16*)(ws + OFS_H0);
  u16*   h1r   = (u16*)(ws + OFS_H1);
  u64*   h1z   = (u64*)(ws + OFS_H1 + 131072ul);   // ring slot 2 (t=0 reads zeros)

  hipMemsetAsync(flags, 0, 4096, stream);
  k_bias <<<32,   256, 0, stream>>>(bih0, bhh0, bih1, bhh1, b0, b1, h1z);
  k_embed<<<8192, 256, 0, stream>>>(inputs, emb, Xb);
  k_pack <<<4096, 256, 0, stream>>>(wih0, (const float*)0, 1024, 0, Wih0p);
  k_pack <<<4096, 256, 0, stream>>>(whh0, (const float*)0, 1024, 0, Whh0p);
  k_pack <<<12288,256, 0, stream>>>(wih1, whh1, 2048, 1024, W1p);

  k_fused<<<256, 256, 0, stream>>>(Wih0p, Whh0p, W1p, b0, b1, Xb,
                                   h0a, h1r, out, flags);
}

// Round 6
// 3858.118 us; speedup vs baseline: 7.2056x; 1.4744x over previous
//
#include <hip/hip_runtime.h>
#include <hip/hip_bf16.h>
#include <stdint.h>

// Bidirectional 2-layer LSTM decoder: B=16, T=512, E=H=1024.
// Round-6 = round-5 with the asm early-clobber fix:
//  - G_LOAD16/G_LOAD8/g_poll2/g_poll1 outputs are "=&v" (early-clobber).
//    Round-5's "=v" let LLVM alias an output with the address pair; the first
//    load clobbered the address -> memory fault -> abort.
//  - All cross-block coherent traffic (h0/h1 data, flags) via inline-asm
//    global_load/store sc0 sc1 (bypass L1+L2, MALL-coherent), batched with a
//    single s_waitcnt vmcnt(0) per batch (plain vmcnt semantics, ~1 RT/batch).
//  - Phase order keeps only the true recurrence on the critical path.
//  - l1 hh weights in LDS (128KB); l0/l1 main weights pinned in VGPRs.

#define TT 512
#define HH 1024

typedef __bf16 bf16x8 __attribute__((ext_vector_type(8)));
typedef float f32x4 __attribute__((ext_vector_type(4)));
typedef unsigned int u32;
typedef unsigned short u16;

#define MFMA __builtin_amdgcn_mfma_f32_16x16x32_bf16

// ---- workspace layout (bytes) ----
#define OFS_FLAGS 0ul            // [4][64] u32 flags (zeroed each launch)
#define OFS_B0    4096ul         // [2][4096] f32
#define OFS_B1    36864ul        // [2][4096] f32
#define OFS_X     69632ul        // [8192][1024] bf16
#define OFS_WIH0  16846848ul     // packed [2][64][4][32][64][8] bf16
#define OFS_WHH0  33624064ul     // same shape
#define OFS_W1    50401280ul     // packed [2][64][4][96][64][8] bf16 (h0 64ks | h1 32ks)
#define OFS_H0    100732928ul    // [512][2][16][1024] bf16
#define OFS_H1    134287360ul    // [3][2][16][1024] bf16 ring
// end ~134.5 MB

__device__ inline u16 f2b(float f){
  union { float f; u32 u; } x{f};
  return (u16)((x.u + 0x7FFFu + ((x.u >> 16) & 1u)) >> 16);
}
__device__ inline float sigm(float x){ return 1.f/(1.f + __expf(-x)); }
__device__ inline float tanh_(float x){ return 2.f*sigm(2.f*x) - 1.f; }

// ---- coherent (MALL-level) access helpers: plain vmcnt semantics ----
__device__ inline u32 g_poll1(const u32* p){
  u32 v;
  asm volatile("global_load_dword %0, %1, off sc0 sc1\n\t"
               "s_waitcnt vmcnt(0)" : "=&v"(v) : "v"(p) : "memory");
  return v;
}
__device__ inline void g_poll2(const u32* p, const u32* q, u32& a, u32& b){
  asm volatile("global_load_dword %0, %2, off sc0 sc1\n\t"
               "global_load_dword %1, %3, off sc0 sc1\n\t"
               "s_waitcnt vmcnt(0)"
               : "=&v"(a), "=&v"(b) : "v"(p), "v"(q) : "memory");
}
__device__ inline void g_store32(u32* p, u32 v){
  asm volatile("global_store_dword %0, %1, off sc0 sc1" :: "v"(p), "v"(v) : "memory");
}

#define G_LOAD16(A, P) asm volatile( \
  "global_load_dwordx4 %0,  %16, off sc0 sc1\n\t" \
  "global_load_dwordx4 %1,  %16, off offset:64 sc0 sc1\n\t" \
  "global_load_dwordx4 %2,  %16, off offset:128 sc0 sc1\n\t" \
  "global_load_dwordx4 %3,  %16, off offset:192 sc0 sc1\n\t" \
  "global_load_dwordx4 %4,  %16, off offset:256 sc0 sc1\n\t" \
  "global_load_dwordx4 %5,  %16, off offset:320 sc0 sc1\n\t" \
  "global_load_dwordx4 %6,  %16, off offset:384 sc0 sc1\n\t" \
  "global_load_dwordx4 %7,  %16, off offset:448 sc0 sc1\n\t" \
  "global_load_dwordx4 %8,  %16, off offset:512 sc0 sc1\n\t" \
  "global_load_dwordx4 %9,  %16, off offset:576 sc0 sc1\n\t" \
  "global_load_dwordx4 %10, %16, off offset:640 sc0 sc1\n\t" \
  "global_load_dwordx4 %11, %16, off offset:704 sc0 sc1\n\t" \
  "global_load_dwordx4 %12, %16, off offset:768 sc0 sc1\n\t" \
  "global_load_dwordx4 %13, %16, off offset:832 sc0 sc1\n\t" \
  "global_load_dwordx4 %14, %16, off offset:896 sc0 sc1\n\t" \
  "global_load_dwordx4 %15, %16, off offset:960 sc0 sc1\n\t" \
  "s_waitcnt vmcnt(0)" \
  : "=&v"(A[0]), "=&v"(A[1]), "=&v"(A[2]), "=&v"(A[3]), \
    "=&v"(A[4]), "=&v"(A[5]), "=&v"(A[6]), "=&v"(A[7]), \
    "=&v"(A[8]), "=&v"(A[9]), "=&v"(A[10]), "=&v"(A[11]), \
    "=&v"(A[12]), "=&v"(A[13]), "=&v"(A[14]), "=&v"(A[15]) \
  : "v"(P) : "memory")

#define G_LOAD8(A, P) asm volatile( \
  "global_load_dwordx4 %0, %8, off sc0 sc1\n\t" \
  "global_load_dwordx4 %1, %8, off offset:64 sc0 sc1\n\t" \
  "global_load_dwordx4 %2, %8, off offset:128 sc0 sc1\n\t" \
  "global_load_dwordx4 %3, %8, off offset:192 sc0 sc1\n\t" \
  "global_load_dwordx4 %4, %8, off offset:256 sc0 sc1\n\t" \
  "global_load_dwordx4 %5, %8, off offset:320 sc0 sc1\n\t" \
  "global_load_dwordx4 %6, %8, off offset:384 sc0 sc1\n\t" \
  "global_load_dwordx4 %7, %8, off offset:448 sc0 sc1\n\t" \
  "s_waitcnt vmcnt(0)" \
  : "=&v"(A[0]), "=&v"(A[1]), "=&v"(A[2]), "=&v"(A[3]), \
    "=&v"(A[4]), "=&v"(A[5]), "=&v"(A[6]), "=&v"(A[7]) \
  : "v"(P) : "memory")

__global__ void k_bias(const float* __restrict__ a0, const float* __restrict__ a1,
                       const float* __restrict__ a2, const float* __restrict__ a3,
                       float* __restrict__ b0, float* __restrict__ b1,
                       unsigned long long* __restrict__ h1z){
  int i = blockIdx.x*256 + threadIdx.x;
  if (i < 8192){ b0[i] = a0[i] + a1[i]; b1[i] = a2[i] + a3[i]; h1z[i] = 0ull; }
}

__global__ void k_embed(const int* __restrict__ inputs, const float* __restrict__ emb,
                        u16* __restrict__ X){
  int row = blockIdx.x;                 // t*16 + b
  int t = row >> 4, b = row & 15;
  int tok = (t == 0) ? 1 : inputs[b*TT + t];   // BOS=1 at t=0
  const float4* src = (const float4*)(emb + (size_t)tok*HH);
  float4 v = src[threadIdx.x];
  ushort4 o = make_ushort4(f2b(v.x), f2b(v.y), f2b(v.z), f2b(v.w));
  ((ushort4*)X)[(size_t)row*256 + threadIdx.x] = o;
}

// pack W[n][k] fp32 -> fragment-major bf16, frag elem j <-> k = ks*32+(l>>4)*8+j
__global__ void k_pack(const float* __restrict__ sA, const float* __restrict__ sB,
                       int KA, int KB, u16* __restrict__ dst){
  int K = KA + KB, KS = K >> 5;
  long idx = (long)blockIdx.x*256 + threadIdx.x;
  long total = 2L*64*4*KS*64;
  if (idx >= total) return;
  int l = (int)(idx & 63);
  long r = idx >> 6;
  int ks = (int)(r % KS); r /= KS;
  int g  = (int)(r & 3);  r >>= 2;
  int jb = (int)(r & 63); r >>= 6;
  int cell = (int)r;
  int n  = g*1024 + jb*16 + (l & 15);
  int k0 = ks*32 + ((l >> 4) << 3);
  const float* s; int kl;
  if (k0 < KA){ s = sA + (long)(cell*4096 + n)*KA; kl = k0; }
  else        { s = sB + (long)(cell*4096 + n)*KB; kl = k0 - KA; }
  float4 f0 = *(const float4*)(s + kl);
  float4 f1 = *(const float4*)(s + kl + 4);
  union { u16 v[8]; int4 q; } o;
  o.v[0]=f2b(f0.x); o.v[1]=f2b(f0.y); o.v[2]=f2b(f0.z); o.v[3]=f2b(f0.w);
  o.v[4]=f2b(f1.x); o.v[5]=f2b(f1.y); o.v[6]=f2b(f1.z); o.v[7]=f2b(f1.w);
  long d = ((((long)cell*64 + jb)*4 + g)*KS + ks)*64 + l;
  ((int4*)dst)[d] = o.q;
}

__global__ __launch_bounds__(256, 1)
void k_fused(const u16* __restrict__ Wih0p, const u16* __restrict__ Whh0p,
             const u16* __restrict__ W1p, const float* __restrict__ b0,
             const float* __restrict__ b1, const u16* __restrict__ Xb,
             u16* h0_all, u16* h1r, float* __restrict__ out, u32* flags)
{
  extern __shared__ char smem[];
  float*  gl   = (float*)smem;                  // [4 waves][4 gates][256] partials
  f32x4*  wlds = (f32x4*)(smem + 16384);        // l1 h1-weights [4][32][64] frags

  const int tid  = threadIdx.x;
  const int wv   = tid >> 6, l = tid & 63;
  const int rowA = l & 15;
  const int kq8  = (l >> 4) * 8;
  const int layer = blockIdx.x >> 7;
  const int bid   = blockIdx.x & 127;
  const int cell  = bid >> 6, jb = bid & 63;
  const int b_ = tid >> 4, j = tid & 15;

  float bias[4];
  {
    const float* bb = (layer == 0 ? b0 : b1) + cell*4096 + jb*16 + rowA;
    #pragma unroll
    for (int g = 0; g < 4; g++) bias[g] = (wv == 0) ? bb[g*1024] : 0.f;
  }
  float creg = 0.f;

  if (layer == 0){
    // wave 0,1: ih (X) ks (wv*16..+15); wave 2,3: hh (h0) ks ((wv-2)*16..+15)
    f32x4 w[4][16];
    {
      const f32x4* src = (const f32x4*)(wv < 2 ? Wih0p : Whh0p)
                       + ((long)(cell*64 + jb)*4)*32*64 + l;
      #pragma unroll
      for (int g = 0; g < 4; g++)
        #pragma unroll
        for (int i = 0; i < 16; i++)
          w[g][i] = src[((long)g*32 + ((wv & 1)*16 + i))*64];
    }
    #pragma unroll
    for (int g = 0; g < 4; g++)
      #pragma unroll
      for (int i = 0; i < 16; i++) asm volatile("" : "+v"(w[g][i]));
    __syncthreads();

    const u32* flr = flags + cell*64;
    u32* myf = flags + cell*64 + jb;
    u32* hdst = (u32*)h0_all;
    const int ko = (wv & 1) * 512;

    for (int t = 0; t < TT; t++){
      f32x4 acc[4];
      #pragma unroll
      for (int g = 0; g < 4; g++) acc[g] = (f32x4){bias[g],bias[g],bias[g],bias[g]};
      if (wv < 2){
        // ih part: no dependency, runs while wave3 polls
        const u16* A = Xb + ((long)t*16 + rowA)*1024 + ko + kq8;
        f32x4 Af[16];
        #pragma unroll
        for (int i = 0; i < 16; i++) Af[i] = *(const f32x4*)(A + i*32);
        #pragma unroll
        for (int i = 0; i < 16; i++)
          #pragma unroll
          for (int g = 0; g < 4; g++)
            acc[g] = MFMA(__builtin_bit_cast(bf16x8, Af[i]),
                          __builtin_bit_cast(bf16x8, w[g][i]), acc[g], 0, 0, 0);
        int r0 = (l >> 4)*4, cj = l & 15;
        #pragma unroll
        for (int g = 0; g < 4; g++)
          #pragma unroll
          for (int i2 = 0; i2 < 4; i2++)
            gl[wv*1024 + g*256 + (r0+i2)*16 + cj] = acc[g][i2];
      } else if (wv == 3 && t > 0){
        while (!__all((int)(g_poll1(flr + l) >= (u32)t))) {}
      }
      __syncthreads();                          // A: h0(t-1) ready
      if (wv >= 2){
        if (t > 0){
          const u16* A = h0_all + (((long)(t-1)*2 + cell)*16 + rowA)*1024 + ko + kq8;
          f32x4 Af[16];
          G_LOAD16(Af, A);
          #pragma unroll
          for (int i = 0; i < 16; i++)
            #pragma unroll
            for (int g = 0; g < 4; g++)
              acc[g] = MFMA(__builtin_bit_cast(bf16x8, Af[i]),
                            __builtin_bit_cast(bf16x8, w[g][i]), acc[g], 0, 0, 0);
        }
        int r0 = (l >> 4)*4, cj = l & 15;
        #pragma unroll
        for (int g = 0; g < 4; g++)
          #pragma unroll
          for (int i2 = 0; i2 < 4; i2++)
            gl[wv*1024 + g*256 + (r0+i2)*16 + cj] = acc[g][i2];
      }
      __syncthreads();                          // B: all partials in gl
      {
        float gi = gl[tid]      + gl[1024+tid] + gl[2048+tid] + gl[3072+tid];
        float gf = gl[256+tid]  + gl[1280+tid] + gl[2304+tid] + gl[3328+tid];
        float gg = gl[512+tid]  + gl[1536+tid] + gl[2560+tid] + gl[3584+tid];
        float go = gl[768+tid]  + gl[1792+tid] + gl[2816+tid] + gl[3840+tid];
        float c2 = sigm(gf)*creg + sigm(gi)*tanh_(gg);
        float h2 = sigm(go)*tanh_(c2);
        creg = c2;
        u32 lo = f2b(h2), hi = __shfl_down(lo, 1);
        if (!(tid & 1)){
          long idx = ((((long)t*2 + cell)*16 + b_)*1024 + jb*16 + j) >> 1;
          g_store32(hdst + idx, lo | (hi << 16));
        }
        asm volatile("s_waitcnt vmcnt(0)" ::: "memory");
      }
      __syncthreads();                          // C: all h stores drained
      if (tid == 0) g_store32(myf, (u32)(t+1));
    }
  } else {
    // l1: h0-part ks wv*16..+15 of [h0f|h0b] (weights in VGPR),
    //     h1-part ks wv*8..+7 (weights in LDS)
    f32x4 w[4][16];
    {
      const f32x4* src = (const f32x4*)W1p + ((long)(cell*64 + jb)*4)*96*64 + l;
      #pragma unroll
      for (int g = 0; g < 4; g++)
        #pragma unroll
        for (int i = 0; i < 16; i++)
          w[g][i] = src[((long)g*96 + wv*16 + i)*64];
      const f32x4* wb = (const f32x4*)W1p + (long)((cell*64 + jb)*4)*96*64;
      for (int i = tid; i < 8192; i += 256){
        int g = i >> 11, ks = (i >> 6) & 31, ll = i & 63;
        wlds[i] = wb[((long)g*96 + 64 + ks)*64 + ll];
      }
    }
    #pragma unroll
    for (int g = 0; g < 4; g++)
      #pragma unroll
      for (int i = 0; i < 16; i++) asm volatile("" : "+v"(w[g][i]));
    __syncthreads();

    const u32* fl0 = flags;
    const u32* fl1 = flags + 64;
    const u32* flo = flags + (2 + cell)*64;
    u32* myf = flags + (2 + cell)*64 + jb;
    const f32x4* wl = wlds + (wv*8)*64 + l;
    u32* hdst = (u32*)h1r;
    int tm = 2, ts = 0;                         // read slot (t-1)%3, write slot t%3

    for (int t = 0; t < TT; t++){
      if (wv == 3){
        const u32 tgt = (u32)(t + 1);
        for (;;){
          u32 a, b; g_poll2(fl0 + l, fl1 + l, a, b);
          if (__all((int)(a >= tgt && b >= tgt))) break;
        }
      }
      __syncthreads();                          // A: h0f(t), h0b(t) ready
      f32x4 acc[4];
      #pragma unroll
      for (int g = 0; g < 4; g++) acc[g] = (f32x4){bias[g],bias[g],bias[g],bias[g]};
      {
        const u16* A = h0_all + (((long)t*2 + (wv >> 1))*16 + rowA)*1024
                     + (wv & 1)*512 + kq8;
        f32x4 Af[16];
        G_LOAD16(Af, A);
        #pragma unroll
        for (int i = 0; i < 16; i++)
          #pragma unroll
          for (int g = 0; g < 4; g++)
            acc[g] = MFMA(__builtin_bit_cast(bf16x8, Af[i]),
                          __builtin_bit_cast(bf16x8, w[g][i]), acc[g], 0, 0, 0);
      }
      if (wv == 3){
        while (!__all((int)(g_poll1(flo + l) >= (u32)t))) {}
      }
      __syncthreads();                          // B: h1(t-1) ready
      {
        const u16* A = h1r + (((long)tm*2 + cell)*16 + rowA)*1024 + wv*256 + kq8;
        f32x4 Af[8];
        G_LOAD8(Af, A);
        #pragma unroll
        for (int i = 0; i < 8; i++)
          #pragma unroll
          for (int g = 0; g < 4; g++)
            acc[g] = MFMA(__builtin_bit_cast(bf16x8, Af[i]),
                          __builtin_bit_cast(bf16x8, wl[(g*32 + i)*64]),
                          acc[g], 0, 0, 0);
      }
      {
        int r0 = (l >> 4)*4, cj = l & 15;
        #pragma unroll
        for (int g = 0; g < 4; g++)
          #pragma unroll
          for (int i2 = 0; i2 < 4; i2++)
            gl[wv*1024 + g*256 + (r0+i2)*16 + cj] = acc[g][i2];
      }
      __syncthreads();                          // C: partials in gl
      {
        float gi = gl[tid]      + gl[1024+tid] + gl[2048+tid] + gl[3072+tid];
        float gf = gl[256+tid]  + gl[1280+tid] + gl[2304+tid] + gl[3328+tid];
        float gg = gl[512+tid]  + gl[1536+tid] + gl[2560+tid] + gl[3584+tid];
        float go = gl[768+tid]  + gl[1792+tid] + gl[2816+tid] + gl[3840+tid];
        float c2 = sigm(gf)*creg + sigm(gi)*tanh_(gg);
        float h2 = sigm(go)*tanh_(c2);
        creg = c2;
        out[((long)b_*TT + t)*2048 + cell*1024 + jb*16 + j] = h2;
        u32 lo = f2b(h2), hi = __shfl_down(lo, 1);
        if (!(tid & 1)){
          long idx = ((((long)ts*2 + cell)*16 + b_)*1024 + jb*16 + j) >> 1;
          g_store32(hdst + idx, lo | (hi << 16));
        }
        asm volatile("s_waitcnt vmcnt(0)" ::: "memory");
      }
      __syncthreads();                          // D: stores drained
      if (tid == 0) g_store32(myf, (u32)(t+1));
      tm = (tm == 2) ? 0 : tm + 1;
      ts = (ts == 2) ? 0 : ts + 1;
    }
  }
}

extern "C" void kernel_launch(void* const* d_in, const int* in_sizes, int n_in,
                              void* d_out, int out_size, void* d_ws, size_t ws_size,
                              hipStream_t stream){
  const int*   inputs = (const int*)d_in[0];
  const float* emb    = (const float*)d_in[1];
  const float* wih0   = (const float*)d_in[2];
  const float* whh0   = (const float*)d_in[3];
  const float* bih0   = (const float*)d_in[4];
  const float* bhh0   = (const float*)d_in[5];
  const float* wih1   = (const float*)d_in[6];
  const float* whh1   = (const float*)d_in[7];
  const float* bih1   = (const float*)d_in[8];
  const float* bhh1   = (const float*)d_in[9];
  float* out = (float*)d_out;
  char* ws = (char*)d_ws;

  u32*   flags = (u32*)(ws + OFS_FLAGS);
  float* b0    = (float*)(ws + OFS_B0);
  float* b1    = (float*)(ws + OFS_B1);
  u16*   Xb    = (u16*)(ws + OFS_X);
  u16*   Wih0p = (u16*)(ws + OFS_WIH0);
  u16*   Whh0p = (u16*)(ws + OFS_WHH0);
  u16*   W1p   = (u16*)(ws + OFS_W1);
  u16*   h0a   = (u16*)(ws + OFS_H0);
  u16*   h1r   = (u16*)(ws + OFS_H1);
  unsigned long long* h1z = (unsigned long long*)(ws + OFS_H1 + 131072ul);

  hipMemsetAsync(flags, 0, 4096, stream);
  k_bias <<<32,   256, 0, stream>>>(bih0, bhh0, bih1, bhh1, b0, b1, h1z);
  k_embed<<<8192, 256, 0, stream>>>(inputs, emb, Xb);
  k_pack <<<4096, 256, 0, stream>>>(wih0, (const float*)0, 1024, 0, Wih0p);
  k_pack <<<4096, 256, 0, stream>>>(whh0, (const float*)0, 1024, 0, Whh0p);
  k_pack <<<12288,256, 0, stream>>>(wih1, whh1, 2048, 1024, W1p);

  const int smem_bytes = 16384 + 131072;
  hipFuncSetAttribute(reinterpret_cast<const void*>(&k_fused),
                      hipFuncAttributeMaxDynamicSharedMemorySize, smem_bytes);
  k_fused<<<256, 256, smem_bytes, stream>>>(Wih0p, Whh0p, W1p, b0, b1, Xb,
                                            h0a, h1r, out, flags);
}